// Round 9
// baseline (179.383 us; speedup 1.0000x reference)
//
#include <hip/hip_runtime.h>
#include <cstdint>

// 4-qubit / 3-layer VQC, B = 2^20, single dispatch.
//
// Identity (verified R4-R8): with merged angle th_w = patch_w + params[0,w,0],
// each output is EXACTLY multilinear in t_w = (1, cos th_w, sin th_w):
//     o_w = sum T^w[a,b,c,d] t0_a t1_b t2_c t3_d
//
// R9: ONE kernel. Block 0 computes the batch-uniform tensor T (4 x 81) via
// the 3^4-grid simulation + mode inversion (~3 us), publishes to d_ws with
// agent-scope stores + release flag. Other blocks acquire-poll the flag
// (cross-XCD-safe), stage T into LDS, and run the bilinear form. Bounded
// spin + local-compute fallback => deadlock-free. Removes the second graph
// node and its ~7 us dispatch gap (R8 showed per-block redundant compute
// costs ~19 us; this pays the prelude once).

typedef float v2f __attribute__((ext_vector_type(2)));

#define MAGIC 0x1F2E3D4Cu
#define NPOLL 200000

// Computes T into LDS (TAf[0..161] = (T0,T1) pairs, TBf[0..161] = (T2,T3)).
// All 256 threads of the block must enter (contains barriers).
__device__ __forceinline__ void compute_T(const float* __restrict__ params,
                                          const int tid,
                                          float (*trig)[4],
                                          float (*bufA)[4],
                                          float (*bufB)[4],
                                          float* TAf, float* TBf) {
    if (tid < 12) {
        float s, c;
        __sincosf(0.5f * params[tid * 2 + 0], &s, &c);
        trig[tid][0] = c; trig[tid][1] = s;
        __sincosf(0.5f * params[tid * 2 + 1], &s, &c);
        trig[tid][2] = c; trig[tid][3] = s;
    }
    __syncthreads();

    if (tid < 81) {
        const int d0 = tid / 27, d1 = (tid / 9) % 3, d2 = (tid / 3) % 3, d3 = tid % 3;
        const float chalf[3] = {1.0f, 0.70710678118654752f, 0.0f};
        const float shalf[3] = {0.0f, 0.70710678118654752f, 1.0f};
        const float ch[4] = {chalf[d0], chalf[d1], chalf[d2], chalf[d3]};
        const float sh[4] = {shalf[d0], shalf[d1], shalf[d2], shalf[d3]};

        float re[16], im[16];
#pragma unroll
        for (int k = 0; k < 16; ++k) {
            float a = ((k >> 3) & 1) ? sh[0] : ch[0];
            a *= ((k >> 2) & 1) ? sh[1] : ch[1];
            a *= ((k >> 1) & 1) ? sh[2] : ch[2];
            a *= (k & 1) ? sh[3] : ch[3];
            re[k] = a; im[k] = 0.0f;
        }

        // layer 0: RZ only (RY merged into grid angle)
#pragma unroll
        for (int w = 0; w < 4; ++w) {
            const int m = 8 >> w;
            const float cz = trig[w][2], sz = trig[w][3];
#pragma unroll
            for (int k = 0; k < 16; ++k) {
                const float r = re[k], q = im[k];
                if (k & m) { re[k] = r * cz - q * sz; im[k] = q * cz + r * sz; }
                else       { re[k] = r * cz + q * sz; im[k] = q * cz - r * sz; }
            }
        }
#pragma unroll
        for (int w = 0; w < 3; ++w) {
            const int cm = 8 >> w, tm = 4 >> w;
#pragma unroll
            for (int b = 0; b < 16; ++b) {
                if ((b & cm) && !(b & tm)) {
                    const int j = b | tm;
                    float t = re[b]; re[b] = re[j]; re[j] = t;
                    t = im[b]; im[b] = im[j]; im[j] = t;
                }
            }
        }

        // layers 1, 2 (layer-2 RZ dropped: probability-invariant)
#pragma unroll
        for (int l = 1; l < 3; ++l) {
#pragma unroll
            for (int w = 0; w < 4; ++w) {
                const int m = 8 >> w, g = l * 4 + w;
                const float cy = trig[g][0], sy = trig[g][1];
#pragma unroll
                for (int b = 0; b < 16; ++b) {
                    if (b & m) continue;
                    const int j = b | m;
                    const float r0 = re[b], r1 = re[j];
                    const float i0 = im[b], i1 = im[j];
                    re[b] = cy * r0 - sy * r1;  re[j] = sy * r0 + cy * r1;
                    im[b] = cy * i0 - sy * i1;  im[j] = sy * i0 + cy * i1;
                }
                if (l != 2) {
                    const float cz = trig[g][2], sz = trig[g][3];
#pragma unroll
                    for (int k = 0; k < 16; ++k) {
                        const float r = re[k], q = im[k];
                        if (k & m) { re[k] = r * cz - q * sz; im[k] = q * cz + r * sz; }
                        else       { re[k] = r * cz + q * sz; im[k] = q * cz - r * sz; }
                    }
                }
            }
#pragma unroll
            for (int w = 0; w < 3; ++w) {
                const int cm = 8 >> w, tm = 4 >> w;
#pragma unroll
                for (int b = 0; b < 16; ++b) {
                    if ((b & cm) && !(b & tm)) {
                        const int j = b | tm;
                        float t = re[b]; re[b] = re[j]; re[j] = t;
                        t = im[b]; im[b] = im[j]; im[j] = t;
                    }
                }
            }
        }

        float ev0 = 0.f, ev1 = 0.f, ev2 = 0.f, ev3 = 0.f;
#pragma unroll
        for (int k = 0; k < 16; ++k) {
            const float pk = re[k] * re[k] + im[k] * im[k];
            ev0 += (k & 8) ? -pk : pk;
            ev1 += (k & 4) ? -pk : pk;
            ev2 += (k & 2) ? -pk : pk;
            ev3 += (k & 1) ? -pk : pk;
        }
        bufA[tid][0] = ev0; bufA[tid][1] = ev1;
        bufA[tid][2] = ev2; bufA[tid][3] = ev3;
    }
    __syncthreads();

    // invert evaluation map mode-by-mode
    const float Minv[3][3] = {{0.5f, 0.0f, 0.5f},
                              {0.5f, 0.0f, -0.5f},
                              {-0.5f, 1.0f, -0.5f}};
    const int strides[4] = {27, 9, 3, 1};
#pragma unroll
    for (int mo = 0; mo < 4; ++mo) {
        const int st = strides[mo];
        float (*src)[4] = (mo & 1) ? bufB : bufA;
        float (*dst)[4] = (mo & 1) ? bufA : bufB;
        for (int idx = tid; idx < 324; idx += 256) {
            const int w = idx & 3, pos = idx >> 2;
            const int dm = (pos / st) % 3;
            const int base = pos - dm * st;
            const float v = Minv[dm][0] * src[base][w]
                          + Minv[dm][1] * src[base + st][w]
                          + Minv[dm][2] * src[base + 2 * st][w];
            if (mo == 3) {
                float* dstT = (w >> 1) ? TBf : TAf;
                dstT[pos * 2 + (w & 1)] = v;
            } else {
                dst[pos][w] = v;
            }
        }
        __syncthreads();
    }
}

__global__ __launch_bounds__(256) void vqc_onepass(const float* __restrict__ patch,
                                                   const float* __restrict__ params,
                                                   float* __restrict__ gws,
                                                   float* __restrict__ out,
                                                   const int B) {
    __shared__ float trig[12][4];
    __shared__ float bufA[81][4];
    __shared__ float bufB[81][4];
    __shared__ v2f TA[81];          // (T0,T1)[pos]
    __shared__ v2f TB[81];          // (T2,T3)[pos]
    __shared__ int s_ready;
    const int tid = threadIdx.x;
    float* TAf = reinterpret_cast<float*>(TA);
    float* TBf = reinterpret_cast<float*>(TB);
    uint32_t* flag = reinterpret_cast<uint32_t*>(gws) + 324;

    if (blockIdx.x == 0) {
        // producer: compute T once, publish to global ws
        compute_T(params, tid, trig, bufA, bufB, TAf, TBf);
        for (int idx = tid; idx < 324; idx += 256) {
            const float v = (idx < 162) ? TAf[idx] : TBf[idx - 162];
            __hip_atomic_store(&gws[idx], v, __ATOMIC_RELAXED,
                               __HIP_MEMORY_SCOPE_AGENT);
        }
        __syncthreads();
        if (tid == 0)
            __hip_atomic_store(flag, MAGIC, __ATOMIC_RELEASE,
                               __HIP_MEMORY_SCOPE_AGENT);
    } else {
        // consumer: bounded acquire-poll, then stage T from ws into LDS
        if (tid == 0) {
            uint32_t v = 0;
            int polls = 0;
            do {
                v = __hip_atomic_load(flag, __ATOMIC_ACQUIRE,
                                      __HIP_MEMORY_SCOPE_AGENT);
                if (v == MAGIC) break;
                __builtin_amdgcn_s_sleep(8);
            } while (++polls < NPOLL);
            s_ready = (v == MAGIC) ? 1 : 0;
        }
        __syncthreads();
        if (s_ready) {
            for (int idx = tid; idx < 324; idx += 256) {
                const float v = __hip_atomic_load(&gws[idx], __ATOMIC_RELAXED,
                                                  __HIP_MEMORY_SCOPE_AGENT);
                if (idx < 162) TAf[idx] = v; else TBf[idx - 162] = v;
            }
            __syncthreads();
        } else {
            // fallback (never expected): compute locally — deadlock-free
            compute_T(params, tid, trig, bufA, bufB, TAf, TBf);
        }
    }

    // ---- per-element bilinear form ----
    const int i = blockIdx.x * 256 + tid;
    if (i >= B) return;

    const float4 p = reinterpret_cast<const float4*>(patch)[i];

    float c0, s0, c1, s1, c2, s2, c3, s3;
    __sincosf(p.x + params[0], &s0, &c0);
    __sincosf(p.y + params[2], &s1, &c1);
    __sincosf(p.z + params[4], &s2, &c2);
    __sincosf(p.w + params[6], &s3, &c3);

    // basis outer products; index 0 == 1 (used implicitly)
    float v01[9], v23[9];
    v01[1] = c1;      v01[2] = s1;
    v01[3] = c0;   v01[4] = c0 * c1; v01[5] = c0 * s1;
    v01[6] = s0;   v01[7] = s0 * c1; v01[8] = s0 * s1;
    v23[1] = c3;      v23[2] = s3;
    v23[3] = c2;   v23[4] = c2 * c3; v23[5] = c2 * s3;
    v23[6] = s2;   v23[7] = s2 * c3; v23[8] = s2 * s3;

    v2f o01, o23;
#pragma unroll
    for (int a = 0; a < 9; ++a) {
        v2f y01 = TA[9 * a];      // b = 0 term: v23[0] == 1
        v2f y23 = TB[9 * a];
#pragma unroll
        for (int b = 1; b < 9; ++b) {
            y01 += TA[9 * a + b] * v23[b];   // packed FMA, LDS broadcast
            y23 += TB[9 * a + b] * v23[b];
        }
        if (a == 0) { o01 = y01; o23 = y23; }      // v01[0] == 1
        else        { o01 += v01[a] * y01; o23 += v01[a] * y23; }
    }

    reinterpret_cast<float4*>(out)[i] = make_float4(o01.x, o01.y, o23.x, o23.y);
}

extern "C" void kernel_launch(void* const* d_in, const int* in_sizes, int n_in,
                              void* d_out, int out_size, void* d_ws, size_t ws_size,
                              hipStream_t stream) {
    const float* patch  = (const float*)d_in[0];
    const float* params = (const float*)d_in[1];
    float* out = (float*)d_out;
    float* gws = (float*)d_ws;
    const int B = in_sizes[0] / 4;

    const int block = 256;
    const int grid = (B + block - 1) / block;
    vqc_onepass<<<grid, block, 0, stream>>>(patch, params, gws, out, B);
}

// Round 10
// 82.898 us; speedup vs baseline: 2.1639x; 2.1639x over previous
//
#include <hip/hip_runtime.h>

// 4-qubit / 3-layer VQC, B = 2^20.
//
// Identity (verified R4-R9): with merged angle th_w = patch_w + params[0,w,0],
// each output is EXACTLY multilinear in t_w = (1, cos th_w, sin th_w):
//     o_w = sum T^w[a,b,c,d] t0_a t1_b t2_c t3_d
// Setup kernel (1 block) simulates the batch-uniform remainder of the circuit
// on the 3^4 grid th in {0, pi/2, pi} and inverts the evaluation map -> T
// (4 x 81 floats in d_ws, as (T0,T1)/(T2,T3) pairs for packed FMA).
//
// R10 vs R5/R7 (best = 79.3): main kernel stages T into LDS once per block
// (81 coalesced float4 loads), hot loop reads uniform-address ds_read_b64
// broadcasts instead of global/constant loads -> no vmcnt stalls inside the
// 160-packed-FMA stream. R8/R9 single-dispatch experiments regressed
// (-19/-100 us) -> two-kernel structure retained.

typedef float v2f __attribute__((ext_vector_type(2)));

// ws layout: [0..161]   pairs (T0[pos], T1[pos]) for pos = 0..80
//            [162..323] pairs (T2[pos], T3[pos])
// pos = 9*(3*d0+d1) + (3*d2+d3), digit d in {0,1,2} <-> basis (1, cos, sin)
__global__ void vqc_setup(const float* __restrict__ params,
                          float* __restrict__ ws) {
    __shared__ float trig[12][4];   // (cy, sy, cz, sz) half-angle per (l,w)
    __shared__ float bufA[81][4];
    __shared__ float bufB[81][4];
    const int tid = threadIdx.x;

    if (tid < 12) {
        float s, c;
        __sincosf(0.5f * params[tid * 2 + 0], &s, &c);
        trig[tid][0] = c; trig[tid][1] = s;
        __sincosf(0.5f * params[tid * 2 + 1], &s, &c);
        trig[tid][2] = c; trig[tid][3] = s;
    }
    __syncthreads();

    if (tid < 81) {
        const int d0 = tid / 27, d1 = (tid / 9) % 3, d2 = (tid / 3) % 3, d3 = tid % 3;
        const float chalf[3] = {1.0f, 0.70710678118654752f, 0.0f};
        const float shalf[3] = {0.0f, 0.70710678118654752f, 1.0f};
        const float ch[4] = {chalf[d0], chalf[d1], chalf[d2], chalf[d3]};
        const float sh[4] = {shalf[d0], shalf[d1], shalf[d2], shalf[d3]};

        float re[16], im[16];
#pragma unroll
        for (int k = 0; k < 16; ++k) {
            float a = ((k >> 3) & 1) ? sh[0] : ch[0];
            a *= ((k >> 2) & 1) ? sh[1] : ch[1];
            a *= ((k >> 1) & 1) ? sh[2] : ch[2];
            a *= (k & 1) ? sh[3] : ch[3];
            re[k] = a; im[k] = 0.0f;
        }

        // ---- layer 0: RZ only (RY merged into grid angle) ----
#pragma unroll
        for (int w = 0; w < 4; ++w) {
            const int m = 8 >> w;
            const float cz = trig[w][2], sz = trig[w][3];
#pragma unroll
            for (int k = 0; k < 16; ++k) {
                const float r = re[k], q = im[k];
                if (k & m) { re[k] = r * cz - q * sz; im[k] = q * cz + r * sz; }
                else       { re[k] = r * cz + q * sz; im[k] = q * cz - r * sz; }
            }
        }
#pragma unroll
        for (int w = 0; w < 3; ++w) {
            const int cm = 8 >> w, tm = 4 >> w;
#pragma unroll
            for (int b = 0; b < 16; ++b) {
                if ((b & cm) && !(b & tm)) {
                    const int j = b | tm;
                    float t = re[b]; re[b] = re[j]; re[j] = t;
                    t = im[b]; im[b] = im[j]; im[j] = t;
                }
            }
        }

        // ---- layers 1, 2 (layer-2 RZ dropped: probability-invariant) ----
#pragma unroll
        for (int l = 1; l < 3; ++l) {
#pragma unroll
            for (int w = 0; w < 4; ++w) {
                const int m = 8 >> w, g = l * 4 + w;
                const float cy = trig[g][0], sy = trig[g][1];
#pragma unroll
                for (int b = 0; b < 16; ++b) {
                    if (b & m) continue;
                    const int j = b | m;
                    const float r0 = re[b], r1 = re[j];
                    const float i0 = im[b], i1 = im[j];
                    re[b] = cy * r0 - sy * r1;  re[j] = sy * r0 + cy * r1;
                    im[b] = cy * i0 - sy * i1;  im[j] = sy * i0 + cy * i1;
                }
                if (l != 2) {
                    const float cz = trig[g][2], sz = trig[g][3];
#pragma unroll
                    for (int k = 0; k < 16; ++k) {
                        const float r = re[k], q = im[k];
                        if (k & m) { re[k] = r * cz - q * sz; im[k] = q * cz + r * sz; }
                        else       { re[k] = r * cz + q * sz; im[k] = q * cz - r * sz; }
                    }
                }
            }
#pragma unroll
            for (int w = 0; w < 3; ++w) {
                const int cm = 8 >> w, tm = 4 >> w;
#pragma unroll
                for (int b = 0; b < 16; ++b) {
                    if ((b & cm) && !(b & tm)) {
                        const int j = b | tm;
                        float t = re[b]; re[b] = re[j]; re[j] = t;
                        t = im[b]; im[b] = im[j]; im[j] = t;
                    }
                }
            }
        }

        float ev0 = 0.f, ev1 = 0.f, ev2 = 0.f, ev3 = 0.f;
#pragma unroll
        for (int k = 0; k < 16; ++k) {
            const float pk = re[k] * re[k] + im[k] * im[k];
            ev0 += (k & 8) ? -pk : pk;
            ev1 += (k & 4) ? -pk : pk;
            ev2 += (k & 2) ? -pk : pk;
            ev3 += (k & 1) ? -pk : pk;
        }
        bufA[tid][0] = ev0; bufA[tid][1] = ev1;
        bufA[tid][2] = ev2; bufA[tid][3] = ev3;
    }
    __syncthreads();

    // ---- invert evaluation map mode-by-mode ----
    // nodes {0, pi/2, pi} -> rows (1,1,0),(1,0,1),(1,-1,0);
    // Minv = [[.5,0,.5],[.5,0,-.5],[-.5,1,-.5]]
    const float Minv[3][3] = {{0.5f, 0.0f, 0.5f},
                              {0.5f, 0.0f, -0.5f},
                              {-0.5f, 1.0f, -0.5f}};
    const int strides[4] = {27, 9, 3, 1};
#pragma unroll
    for (int mo = 0; mo < 4; ++mo) {
        const int st = strides[mo];
        float (*src)[4] = (mo & 1) ? bufB : bufA;
        float (*dst)[4] = (mo & 1) ? bufA : bufB;
        for (int idx = tid; idx < 324; idx += blockDim.x) {
            const int w = idx & 3, pos = idx >> 2;
            const int dm = (pos / st) % 3;
            const int base = pos - dm * st;
            const float v = Minv[dm][0] * src[base][w]
                          + Minv[dm][1] * src[base + st][w]
                          + Minv[dm][2] * src[base + 2 * st][w];
            if (mo == 3) {
                const int half = (w >> 1);
                ws[half * 162 + pos * 2 + (w & 1)] = v;
            } else {
                dst[pos][w] = v;
            }
        }
        __syncthreads();
    }
}

__global__ __launch_bounds__(256) void vqc_main(const float* __restrict__ patch,
                                                const float* __restrict__ params,
                                                const float* __restrict__ ws,
                                                float* __restrict__ out,
                                                const int B) {
    // Tsh[0..80] = (T0,T1) pairs, Tsh[81..161] = (T2,T3) pairs
    __shared__ v2f Tsh[162];
    const int tid = threadIdx.x;

    // one coalesced float4 load per thread stages all 324 floats
    if (tid < 81)
        reinterpret_cast<float4*>(Tsh)[tid] =
            reinterpret_cast<const float4*>(ws)[tid];
    __syncthreads();

    const int i = blockIdx.x * 256 + tid;
    if (i >= B) return;

    const float4 p = reinterpret_cast<const float4*>(patch)[i];

    float c0, s0, c1, s1, c2, s2, c3, s3;
    __sincosf(p.x + params[0], &s0, &c0);
    __sincosf(p.y + params[2], &s1, &c1);
    __sincosf(p.z + params[4], &s2, &c2);
    __sincosf(p.w + params[6], &s3, &c3);

    // basis outer products; index 0 == 1 (used implicitly)
    float v01[9], v23[9];
    v01[1] = c1;      v01[2] = s1;
    v01[3] = c0;   v01[4] = c0 * c1; v01[5] = c0 * s1;
    v01[6] = s0;   v01[7] = s0 * c1; v01[8] = s0 * s1;
    v23[1] = c3;      v23[2] = s3;
    v23[3] = c2;   v23[4] = c2 * c3; v23[5] = c2 * s3;
    v23[6] = s2;   v23[7] = s2 * c3; v23[8] = s2 * s3;

    const v2f* __restrict__ TA = Tsh;        // (T0,T1)[pos]
    const v2f* __restrict__ TB = Tsh + 81;   // (T2,T3)[pos]

    v2f o01, o23;
#pragma unroll
    for (int a = 0; a < 9; ++a) {
        v2f y01 = TA[9 * a];      // b = 0 term: v23[0] == 1
        v2f y23 = TB[9 * a];
#pragma unroll
        for (int b = 1; b < 9; ++b) {
            y01 += TA[9 * a + b] * v23[b];   // packed FMA, LDS broadcast coeff
            y23 += TB[9 * a + b] * v23[b];
        }
        if (a == 0) { o01 = y01; o23 = y23; }      // v01[0] == 1
        else        { o01 += v01[a] * y01; o23 += v01[a] * y23; }
    }

    reinterpret_cast<float4*>(out)[i] = make_float4(o01.x, o01.y, o23.x, o23.y);
}

extern "C" void kernel_launch(void* const* d_in, const int* in_sizes, int n_in,
                              void* d_out, int out_size, void* d_ws, size_t ws_size,
                              hipStream_t stream) {
    const float* patch  = (const float*)d_in[0];
    const float* params = (const float*)d_in[1];
    float* out = (float*)d_out;
    float* ws  = (float*)d_ws;
    const int B = in_sizes[0] / 4;

    vqc_setup<<<1, 128, 0, stream>>>(params, ws);

    const int block = 256;
    const int grid = (B + block - 1) / block;
    vqc_main<<<grid, block, 0, stream>>>(patch, params, ws, out, B);
}